// Round 4
// baseline (194.050 us; speedup 1.0000x reference)
//
#include <hip/hip_runtime.h>
#include <stdint.h>

typedef __attribute__((ext_vector_type(4))) float f32x4;
typedef __attribute__((ext_vector_type(8))) short s16x8;
typedef __attribute__((address_space(1))) const char g8_t;
typedef __attribute__((address_space(3))) char lds8_t;

// ---- geometry (fixed problem) ----
// x: (16,64,128,128) fp32; weight: (64,64,6,6) fp32 (already Winograd-domain); bias fp32
// out: (16,64,128,128) fp32. 4x4 tiles, nt=32/dim, superblocks 8x8 per image, PAD=1.
#define WB_BYTES 294912              // 36*64*64 bf16

__device__ __forceinline__ short f2bf(float f) {
    uint32_t u = __builtin_bit_cast(uint32_t, f);
    u = u + 0x7FFFu + ((u >> 16) & 1u);          // round-to-nearest-even
    return (short)(u >> 16);
}

// ---------------- Kernel 0: weight relayout fp32(co,cin,ab) -> bf16 [ab][co*64+cin] ----------------
__global__ __launch_bounds__(256) void wtrans(const float* __restrict__ wf, short* __restrict__ wb) {
    int tid = blockIdx.x * 256 + threadIdx.x;    // 0..4095 == co*64+cin
    const float* src = wf + tid * 36;
    float w[36];
#pragma unroll
    for (int i = 0; i < 9; i++) {
        f32x4 v = *(const f32x4*)(src + 4 * i);
        w[4*i+0] = v[0]; w[4*i+1] = v[1]; w[4*i+2] = v[2]; w[4*i+3] = v[3];
    }
#pragma unroll
    for (int ab = 0; ab < 36; ab++) wb[ab * 4096 + tid] = f2bf(w[ab]);
}

// ---------------- Fused kernel, ab-split ----------------
// Block = (superblock sb of 16 tiles) x (cout group cog of 16 couts). 256 thr = 4 waves.
// Wave w owns ab-planes 9w..9w+8 -> acc = 9 f32x4 = 36 regs (vs 144) -> 3 blocks/CU.
// cin in 4 quarters of 16: X staged via global_load_lds into [cin16][row18][col24] (lane-linear),
// transform -> Vs[36][tile16][cin16] bf16, B-frags assembled across quarter pairs (predicated
// half-wave reads), 9 K=32 MFMAs per cin-half per wave. Epilogue: M exchange through LDS (pad 257).
// bid mapping puts the 4 cog-siblings of one sb on the SAME XCD (bid%8 equal) for L2 halo reuse.
__global__ __launch_bounds__(256, 3) void wino_fused(const float* __restrict__ x,
                                                     const short* __restrict__ wb,
                                                     const float* __restrict__ bias,
                                                     float* __restrict__ out) {
    __shared__ __align__(16) union UU {
        struct { float X[16 * 432]; short Vs[36 * 256]; } s;   // 27648 B + 18432 B = 46080 B
        float Mx[36 * 257];                                     // 37008 B
    } u;

    int t = threadIdx.x;
    int lane = t & 63;
    int lo = lane & 15;                          // MFMA m (cout-local) / n (tile) index
    int kq = lane >> 4;                          // MFMA k-quad
    int wav = t >> 6;
    int wab0 = wav * 9;                          // this wave's first ab-plane

    int bid = blockIdx.x;                        // 4096 blocks: [g 128][cog 4][s8 8]
    int g = bid >> 5;
    int cog = (bid >> 3) & 3;
    int sb = g * 8 + (bid & 7);                  // 0..1023 ; siblings differ only in cog -> same XCD
    int n = sb >> 6;
    int sb6 = sb & 63;
    int p0 = (sb6 >> 3) << 2;                    // tile-row origin: 0,4,..,28
    int q0 = (sb6 & 7) << 2;
    const float* xb = x + (size_t)n * 64 * 16384;
    int row0 = 4 * p0 - 1;
    int col0 = 4 * q0 - 4;                       // X col j <-> global col col0+j ; needed j: 3..20
    bool bnd = (p0 == 0) | (p0 == 28) | (q0 == 0) | (q0 == 28);

    int ci = t & 15;                             // transform task: cin within quarter
    int tile = t >> 4;                           // transform task: tile 0..15
    int ttp = tile >> 2, ttq = tile & 3;

    f32x4 acc[9];
#pragma unroll
    for (int i = 0; i < 9; i++) acc[i] = (f32x4){0.f, 0.f, 0.f, 0.f};
    s16x8 bfrag[9];

    for (int rq = 0; rq < 4; rq++) {
        // ---- stage X quarter: 16 cin x 18 rows x 6 f4-chunks = 1728 chunks via global_load_lds ----
#pragma unroll
        for (int i = 0; i < 7; i++) {
            int k = i * 256 + t;
            if (k < 1728) {
                int cc = k / 108;
                int rem = k - cc * 108;
                int row = rem / 6;
                int c4 = rem - row * 6;
                int gr = row0 + row;
                int gc = col0 + 4 * c4;
                bool ok = ((unsigned)gr < 128u) && ((unsigned)gc <= 124u);
                const float* src = ok ? (xb + ((size_t)((rq * 16 + cc) * 128 + gr)) * 128 + gc) : xb;
                lds8_t* dst = (lds8_t*)u.s.X + (size_t)(i * 256 + (t & ~63)) * 16;
                __builtin_amdgcn_global_load_lds((g8_t*)src, dst, 16, 0, 0);
            }
        }
        __syncthreads();                         // X staged (drains glds)

        if (bnd) {                               // zero OOB chunks (block-uniform branch)
            if (p0 == 0 && t < 96)  { int c = t / 6, c4 = t - 6 * c;  *(f32x4*)&u.s.X[(c * 108 + 0 * 6 + c4) * 4] = (f32x4){0,0,0,0}; }
            if (p0 == 28 && t < 96) { int c = t / 6, c4 = t - 6 * c;  *(f32x4*)&u.s.X[(c * 108 + 17 * 6 + c4) * 4] = (f32x4){0,0,0,0}; }
            if (q0 == 0)  { for (int z = t; z < 288; z += 256) { int c = z / 18, row = z - 18 * c; *(f32x4*)&u.s.X[(c * 108 + row * 6 + 0) * 4] = (f32x4){0,0,0,0}; } }
            if (q0 == 28) { for (int z = t; z < 288; z += 256) { int c = z / 18, row = z - 18 * c; *(f32x4*)&u.s.X[(c * 108 + row * 6 + 5) * 4] = (f32x4){0,0,0,0}; } }
            __syncthreads();
        }

        // ---- transform: thread (tile,ci): rows 4tp..4tp+5, cols j=4tq+3..4tq+8 ----
        {
            const float* Xr = u.s.X + ci * 432 + (4 * ttp) * 24 + 4 * ttq;  // 16B-aligned row base
            float E[6][6];                       // E = d * BT^T (row pass)
#pragma unroll
            for (int rr = 0; rr < 6; rr++) {
                f32x4 v0 = *(const f32x4*)(Xr + rr * 24);        // cols j-3..j (only [3] used)
                f32x4 v1 = *(const f32x4*)(Xr + rr * 24 + 4);
                float v2 = Xr[rr * 24 + 8];
                float m0 = v0[3], m1 = v1[0], m2 = v1[1], m3 = v1[2], m4 = v1[3], m5 = v2;
                float e = fmaf(-4.f, m2, m4);
                float f = fmaf(-4.f, m1, m3);
                float gg = m4 - m2;
                float h = m3 - m1;
                E[rr][0] = fmaf(4.f, m0 - m2, gg);
                E[rr][1] = e + f;
                E[rr][2] = e - f;
                E[rr][3] = fmaf(2.f, h, gg);
                E[rr][4] = fmaf(-2.f, h, gg);
                E[rr][5] = fmaf(4.f, m1 - m3, m5 - m3);
            }
            short* vbw = u.s.Vs + tile * 16 + ci;                 // + (a*6+b)*256
#pragma unroll
            for (int b = 0; b < 6; b++) {        // col pass: V[a][b] = BT . E[.][b]
                float m0 = E[0][b], m1 = E[1][b], m2 = E[2][b], m3 = E[3][b], m4 = E[4][b], m5 = E[5][b];
                float e = fmaf(-4.f, m2, m4);
                float f = fmaf(-4.f, m1, m3);
                float gg = m4 - m2;
                float h = m3 - m1;
                vbw[(0 * 6 + b) * 256] = f2bf(fmaf(4.f, m0 - m2, gg));
                vbw[(1 * 6 + b) * 256] = f2bf(e + f);
                vbw[(2 * 6 + b) * 256] = f2bf(e - f);
                vbw[(3 * 6 + b) * 256] = f2bf(fmaf(2.f, h, gg));
                vbw[(4 * 6 + b) * 256] = f2bf(fmaf(-2.f, h, gg));
                vbw[(5 * 6 + b) * 256] = f2bf(fmaf(4.f, m1 - m3, m5 - m3));
            }
        }
        __syncthreads();                         // Vs ready

        // ---- B-frag assembly: lanes kq{0,1} fill on even quarter, kq{2,3} on odd ----
        int qpar = rq & 1;
        if ((kq >> 1) == qpar) {
            int koff = (kq & 1) * 8;
#pragma unroll
            for (int abl = 0; abl < 9; abl++)
                bfrag[abl] = *(const s16x8*)(u.s.Vs + (wab0 + abl) * 256 + lo * 16 + koff);
        }
        if (qpar) {                              // both quarters of this cin-half done -> 9 MFMAs
            int half = rq >> 1;
            const short* wba = wb + (cog * 16 + lo) * 64 + half * 32 + kq * 8;
#pragma unroll
            for (int abl = 0; abl < 9; abl++) {
                s16x8 a = *(const s16x8*)(wba + (wab0 + abl) * 4096);
                acc[abl] = __builtin_amdgcn_mfma_f32_16x16x32_bf16(a, bfrag[abl], acc[abl], 0, 0, 0);
            }
        }
        // next stage's X writes / Vs writes are fenced by the next iteration's syncthreads
    }
    __syncthreads();                             // all B-reads done; union is free for Mx

    // ---- epilogue: exchange M through LDS (ab-plane stride 257 -> conflict-free reads) ----
#pragma unroll
    for (int abl = 0; abl < 9; abl++)
#pragma unroll
        for (int rr = 0; rr < 4; rr++)
            u.Mx[(wab0 + abl) * 257 + (kq * 4 + rr) * 16 + lo] = acc[abl][rr];
    __syncthreads();

    {
        int c16 = t >> 4;                        // this thread: cout-local c16, tile = t&15
        int tl = t & 15;
        int co = cog * 16 + c16;
        float bv = bias[co];
        float z[4][6];
#pragma unroll
        for (int b = 0; b < 6; b++) {
            float m0 = u.Mx[(0 * 6 + b) * 257 + c16 * 16 + tl];
            float m1 = u.Mx[(1 * 6 + b) * 257 + c16 * 16 + tl];
            float m2 = u.Mx[(2 * 6 + b) * 257 + c16 * 16 + tl];
            float m3 = u.Mx[(3 * 6 + b) * 257 + c16 * 16 + tl];
            float m4 = u.Mx[(4 * 6 + b) * 257 + c16 * 16 + tl];
            float m5 = u.Mx[(5 * 6 + b) * 257 + c16 * 16 + tl];
            float s1 = m1 + m2, d1 = m1 - m2, s2 = m3 + m4, d2 = m3 - m4;
            z[0][b] = m0 + s1 + s2;
            z[1][b] = fmaf(2.f, d2, d1);
            z[2][b] = fmaf(4.f, s2, s1);
            z[3][b] = fmaf(8.f, d2, d1) + m5;
        }
        int p = p0 + (tl >> 2), q = q0 + (tl & 3);
        float* ob = out + ((size_t)(n * 64 + co) * 128 + 4 * p) * 128 + 4 * q;
#pragma unroll
        for (int xr = 0; xr < 4; xr++) {
            float s1 = z[xr][1] + z[xr][2], d1 = z[xr][1] - z[xr][2];
            float s2 = z[xr][3] + z[xr][4], d2 = z[xr][3] - z[xr][4];
            f32x4 y;
            y[0] = z[xr][0] + s1 + s2 + bv;
            y[1] = fmaf(2.f, d2, d1) + bv;
            y[2] = fmaf(4.f, s2, s1) + bv;
            y[3] = fmaf(8.f, d2, d1) + z[xr][5] + bv;
            *(f32x4*)(ob + xr * 128) = y;
        }
    }
}

extern "C" void kernel_launch(void* const* d_in, const int* in_sizes, int n_in,
                              void* d_out, int out_size, void* d_ws, size_t ws_size,
                              hipStream_t stream) {
    const float* x    = (const float*)d_in[0];
    const float* wf   = (const float*)d_in[1];
    const float* bias = (const float*)d_in[2];
    float* out = (float*)d_out;

    if (ws_size < WB_BYTES) return;
    short* wb = (short*)d_ws;

    wtrans<<<16, 256, 0, stream>>>(wf, wb);
    wino_fused<<<4096, 256, 0, stream>>>(x, wb, bias, out);
}